// Round 1
// baseline (237.692 us; speedup 1.0000x reference)
//
#include <hip/hip_runtime.h>
#include <stdint.h>

// hetero_effect_graph: 2-layer RGCN over dense level-partitioned bipartite graph.
// Pipeline:
//  k_prep : transpose+bf16 root1,root2,W1[1..5],W2[1..5]  (B operands want [d][k])
//  k_lev  : lev = ceil(w*6)-1 (int8), per-row relation counts -> inv[NE][8],
//           xe->bf16, d_out := b1 (conv1 accumulator init)
//  k_gemm : m1 = relu(xm@root1+b1) (bf16); Z1t[r]=xm@W1[r], Z2t[r]=m1@W2[r] (transposed bf16)
//  k_conv : conv = sum_r (inv_r*mask_r) @ Z_r  via bf16 MFMA with masks built in-register
//           from lev bytes (inv folded into A => single shared accumulator), plus
//           x@root on split-k block 0; f32 atomicAdd epilogue. Split-K=8 for occupancy.
//  k_fin  : e1 = relu(acc) -> bf16, d_out := b2
//  k_conv : conv2 -> d_out (f32)

#define NE 10000
#define NM 2048
#define NEPAD 10112   // 79 * 128
#define MTILES 79
#define KSPLIT 8

typedef short bf8_t __attribute__((ext_vector_type(8)));   // 8 bf16 in 4 VGPRs (MFMA A/B frag)
typedef float f16f  __attribute__((ext_vector_type(16)));  // 32x32 MFMA accumulator

__device__ __forceinline__ uint16_t f2bf(float f){
  uint32_t u = __float_as_uint(f);
  u += 0x7FFFu + ((u >> 16) & 1u);   // round-to-nearest-even
  return (uint16_t)(u >> 16);
}

__device__ __forceinline__ f16f mfma32(bf8_t a, bf8_t b, f16f c){
  return __builtin_amdgcn_mfma_f32_32x32x16_bf16(a, b, c, 0, 0, 0);
}

// ---- transpose + bf16 convert the small weight matrices ----
__global__ __launch_bounds__(256) void k_prep(
    const float* __restrict__ root1, const float* __restrict__ root2,
    const float* __restrict__ W1, const float* __restrict__ W2,
    uint16_t* __restrict__ r1t, uint16_t* __restrict__ r2t,
    uint16_t* __restrict__ w1t, uint16_t* __restrict__ w2t){
  int idx = blockIdx.x*256 + threadIdx.x;   // 0..196607 (12 slabs of 128x128)
  int slab = idx >> 14;
  int pos  = idx & 16383;
  int d = pos >> 7, k = pos & 127;
  float v; uint16_t* dst;
  if (slab == 0)      { v = root1[k*128 + d]; dst = r1t; }
  else if (slab == 1) { v = root2[k*128 + d]; dst = r2t; }
  else if (slab < 7)  { v = W1[(slab-1)*16384 + k*128 + d]; dst = w1t + (slab-2)*16384; }
  else                { v = W2[(slab-6)*16384 + k*128 + d]; dst = w2t + (slab-7)*16384; }
  dst[pos] = f2bf(v);   // t[d][k] = src[k][d]
}

// ---- per-entity-row: lev bytes, relation counts -> inv, xe->bf16, out := b1 ----
__global__ __launch_bounds__(256) void k_lev(
    const float* __restrict__ w, const float* __restrict__ xe,
    const float* __restrict__ b1,
    uint8_t* __restrict__ lev, float* __restrict__ inv,
    uint16_t* __restrict__ xebf, float* __restrict__ out, int use_lev){
  int row = blockIdx.x, tid = threadIdx.x;
  if (row >= NE){   // pad rows: no relations, zero inv / xebf
    if (use_lev) *(uint2*)(lev + (size_t)row*NM + tid*8) = make_uint2(0xFFFFFFFFu, 0xFFFFFFFFu);
    if (tid < 8)   inv[row*8 + tid] = 0.f;
    if (tid < 128) xebf[(size_t)row*128 + tid] = 0;
    return;
  }
  const float4* wr = (const float4*)(w + (size_t)row*NM);
  float4 v0 = wr[tid*2], v1 = wr[tid*2 + 1];
  float wv[8] = {v0.x,v0.y,v0.z,v0.w, v1.x,v1.y,v1.z,v1.w};
  unsigned long long cnt = 0ull;       // 5 x 12-bit packed counters (max 2048 < 4096)
  uint32_t plo = 0, phi = 0;
  #pragma unroll
  for (int e = 0; e < 8; e++){
    int le = (int)ceilf(wv[e]*6.0f) - 1;     // identical f32 ops to jnp.ceil(w*6)-1
    if (le >= 1) cnt += 1ull << (12*(le-1)); // le <= 5 since w < 1
    uint32_t b = (uint32_t)(uint8_t)le;      // -1 -> 0xFF (never matches r=1..5)
    if (e < 4) plo |= b << (8*e); else phi |= b << (8*(e-4));
  }
  if (use_lev) *(uint2*)(lev + (size_t)row*NM + tid*8) = make_uint2(plo, phi);
  unsigned long long c = cnt;
  #pragma unroll
  for (int off = 32; off >= 1; off >>= 1) c += __shfl_down(c, (unsigned)off);
  __shared__ unsigned long long red[4];
  int lane = tid & 63, wid = tid >> 6;
  if (lane == 0) red[wid] = c;
  __syncthreads();
  if (tid == 0){
    unsigned long long t = red[0] + red[1] + red[2] + red[3];
    inv[row*8 + 0] = 0.f; inv[row*8 + 6] = 0.f; inv[row*8 + 7] = 0.f;
    #pragma unroll
    for (int r = 1; r <= 5; r++){
      uint32_t cc = (uint32_t)((t >> (12*(r-1))) & 0xFFFull);
      inv[row*8 + r] = cc ? 1.0f/(float)cc : 0.f;
    }
  }
  if (tid < 128){
    xebf[(size_t)row*128 + tid] = f2bf(xe[(size_t)row*128 + tid]);
    out[(size_t)row*128 + tid] = b1[tid];   // conv1 accumulator initialized with bias
  }
}

// ---- small GEMM: C[M=2048 x 128] = A[2048x128] @ B[128x128] (+bias,relu) ----
// B given transposed bf16 [d][k]. TRANS: write C transposed ([d][j]) for Z buffers.
template<bool ABF16, bool BIASRELU, bool TRANS>
__global__ __launch_bounds__(256) void k_gemm(
    const float* __restrict__ Af, const uint16_t* __restrict__ Ab,
    const uint16_t* __restrict__ Bt, const float* __restrict__ bias,
    uint16_t* __restrict__ outp){
  int tid = threadIdx.x;
  int lane = tid & 63, wid = tid >> 6;
  int l31 = lane & 31, g = lane >> 5;
  const uint16_t* B = Bt + (size_t)blockIdx.y * 16384;
  int arow = blockIdx.x*128 + wid*32 + l31;
  f16f acc[4];
  #pragma unroll
  for (int n = 0; n < 4; n++)
    #pragma unroll
    for (int i = 0; i < 16; i++) acc[n][i] = 0.f;
  #pragma unroll
  for (int ksI = 0; ksI < 8; ksI++){
    int k0 = ksI*16 + g*8;
    bf8_t a;
    if (ABF16){
      a = *(const bf8_t*)(Ab + (size_t)arow*128 + k0);
    } else {
      const float* ap = Af + (size_t)arow*128 + k0;
      float4 f0 = *(const float4*)ap;
      float4 f1 = *(const float4*)(ap + 4);
      union { uint16_t u[8]; bf8_t v; } ua;
      ua.u[0]=f2bf(f0.x); ua.u[1]=f2bf(f0.y); ua.u[2]=f2bf(f0.z); ua.u[3]=f2bf(f0.w);
      ua.u[4]=f2bf(f1.x); ua.u[5]=f2bf(f1.y); ua.u[6]=f2bf(f1.z); ua.u[7]=f2bf(f1.w);
      a = ua.v;
    }
    #pragma unroll
    for (int n = 0; n < 4; n++){
      bf8_t b = *(const bf8_t*)(B + (size_t)(n*32 + l31)*128 + k0);
      acc[n] = mfma32(a, b, acc[n]);
    }
  }
  #pragma unroll
  for (int n = 0; n < 4; n++){
    int colg = n*32 + l31;
    float bv = BIASRELU ? bias[colg] : 0.f;
    #pragma unroll
    for (int v = 0; v < 16; v++){
      int rowl = (v&3) + 8*(v>>2) + 4*g;     // verified 32x32 C/D layout
      int rg = blockIdx.x*128 + wid*32 + rowl;
      float val = acc[n][v] + bv;
      if (BIASRELU) val = fmaxf(val, 0.f);
      if (TRANS) outp[(size_t)blockIdx.y*262144 + (size_t)colg*2048 + rg] = f2bf(val);
      else       outp[(size_t)rg*128 + colg] = f2bf(val);
    }
  }
}

// ---- masked RGCN conv: tgt += sum_r (inv_r * mask_r) @ Z_r  [+ Aroot @ rootT on ks==0] ----
// Block: 128(M) x 128(N), 4 waves in 2Mx2N; wave: 2 M-tiles x 2 N-tiles of 32x32 MFMA.
template<bool USE_LEV>
__global__ __launch_bounds__(256, 2) void k_conv(
    const uint8_t* __restrict__ lev, const float* __restrict__ wmat,
    const float* __restrict__ inv, const uint16_t* __restrict__ zt,
    const uint16_t* __restrict__ aroot, const uint16_t* __restrict__ rt,
    float* __restrict__ tgt){
  int tid = threadIdx.x;
  int lane = tid & 63, wid = tid >> 6;
  int wm = wid >> 1, wn = wid & 1;
  int l31 = lane & 31, g = lane >> 5;
  int brow = blockIdx.x*128;
  int ks = blockIdx.y;

  // per-lane A-row inverse-degree bf16 bits (low/high half), per M-tile and relation
  uint32_t lo[2][5], hi[2][5];
  #pragma unroll
  for (int mt = 0; mt < 2; mt++){
    int rg = brow + 64*wm + 32*mt + l31;
    #pragma unroll
    for (int r = 1; r <= 5; r++){
      uint32_t bits = (uint32_t)f2bf(inv[(size_t)rg*8 + r]);
      lo[mt][r-1] = bits;
      hi[mt][r-1] = bits << 16;
    }
  }

  f16f acc[2][2];
  #pragma unroll
  for (int a0=0;a0<2;a0++)
    #pragma unroll
    for (int b0=0;b0<2;b0++)
      #pragma unroll
      for (int i=0;i<16;i++) acc[a0][b0][i]=0.f;

  int kbase = ks*256;
  #pragma unroll 2
  for (int kk = 0; kk < 16; kk++){
    int k0 = kbase + kk*16 + g*8;
    uint32_t eb[2][8];
    #pragma unroll
    for (int mt = 0; mt < 2; mt++){
      int rg = brow + 64*wm + 32*mt + l31;
      uint32_t plo, phi;
      if (USE_LEV){
        uint2 L = *(const uint2*)(lev + (size_t)rg*NM + k0);
        plo = L.x; phi = L.y;
      } else {
        if (rg < NE){
          const float* wp = wmat + (size_t)rg*NM + k0;
          float4 f0 = *(const float4*)wp;
          float4 f1 = *(const float4*)(wp + 4);
          float wv[8] = {f0.x,f0.y,f0.z,f0.w, f1.x,f1.y,f1.z,f1.w};
          plo = 0; phi = 0;
          #pragma unroll
          for (int e=0;e<8;e++){
            int le = (int)ceilf(wv[e]*6.0f) - 1;
            uint32_t b = (uint32_t)(uint8_t)le;
            if (e<4) plo |= b << (8*e); else phi |= b << (8*(e-4));
          }
        } else { plo = 0xFFFFFFFFu; phi = 0xFFFFFFFFu; }
      }
      eb[mt][0]= plo      & 0xFF; eb[mt][1]=(plo>>8) & 0xFF;
      eb[mt][2]=(plo>>16) & 0xFF; eb[mt][3]= plo>>24;
      eb[mt][4]= phi      & 0xFF; eb[mt][5]=(phi>>8) & 0xFF;
      eb[mt][6]=(phi>>16) & 0xFF; eb[mt][7]= phi>>24;
    }
    #pragma unroll
    for (int r = 1; r <= 5; r++){
      const uint16_t* zb = zt + (size_t)(r-1)*262144;   // Z_r^T [d][j] bf16
      bf8_t bn0 = *(const bf8_t*)(zb + (size_t)(64*wn      + l31)*NM + k0);
      bf8_t bn1 = *(const bf8_t*)(zb + (size_t)(64*wn + 32 + l31)*NM + k0);
      #pragma unroll
      for (int mt = 0; mt < 2; mt++){
        union { uint32_t u[4]; bf8_t v; } A;
        #pragma unroll
        for (int p = 0; p < 4; p++){
          uint32_t m0 = (eb[mt][2*p]   == (uint32_t)r) ? lo[mt][r-1] : 0u;
          uint32_t m1 = (eb[mt][2*p+1] == (uint32_t)r) ? hi[mt][r-1] : 0u;
          A.u[p] = m0 | m1;
        }
        acc[mt][0] = mfma32(A.v, bn0, acc[mt][0]);
        acc[mt][1] = mfma32(A.v, bn1, acc[mt][1]);
      }
    }
  }

  if (ks == 0){  // dense root-matmul part (K = 128)
    #pragma unroll
    for (int kk = 0; kk < 8; kk++){
      int k0 = kk*16 + g*8;
      bf8_t a0 = *(const bf8_t*)(aroot + (size_t)(brow + 64*wm      + l31)*128 + k0);
      bf8_t a1 = *(const bf8_t*)(aroot + (size_t)(brow + 64*wm + 32 + l31)*128 + k0);
      bf8_t rb0 = *(const bf8_t*)(rt + (size_t)(64*wn      + l31)*128 + k0);
      bf8_t rb1 = *(const bf8_t*)(rt + (size_t)(64*wn + 32 + l31)*128 + k0);
      acc[0][0] = mfma32(a0, rb0, acc[0][0]);
      acc[0][1] = mfma32(a0, rb1, acc[0][1]);
      acc[1][0] = mfma32(a1, rb0, acc[1][0]);
      acc[1][1] = mfma32(a1, rb1, acc[1][1]);
    }
  }

  #pragma unroll
  for (int mt = 0; mt < 2; mt++){
    #pragma unroll
    for (int nt = 0; nt < 2; nt++){
      int colg = 64*wn + 32*nt + l31;
      #pragma unroll
      for (int v = 0; v < 16; v++){
        int rowl = (v&3) + 8*(v>>2) + 4*g;
        int rg = brow + 64*wm + 32*mt + rowl;
        if (rg < NE) unsafeAtomicAdd(&tgt[(size_t)rg*128 + colg], acc[mt][nt][v]);
      }
    }
  }
}

// ---- e1 = relu(acc) -> bf16; reset d_out := b2 for conv2 ----
__global__ __launch_bounds__(256) void k_fin(
    float* __restrict__ dout, const float* __restrict__ b2,
    uint16_t* __restrict__ e1bf){
  int idx = blockIdx.x*256 + threadIdx.x;
  if (idx < NE*128){
    float v = dout[idx];
    e1bf[idx] = f2bf(fmaxf(v, 0.f));
    dout[idx] = b2[idx & 127];
  } else if (idx < NEPAD*128){
    e1bf[idx] = 0;
  }
}

extern "C" void kernel_launch(void* const* d_in, const int* in_sizes, int n_in,
                              void* d_out, int out_size, void* d_ws, size_t ws_size,
                              hipStream_t stream){
  const float* xe  = (const float*)d_in[0];   // emb_entity [1,NE,128]
  const float* xm  = (const float*)d_in[1];   // emb_mole   [1,NM,128]
  const float* w   = (const float*)d_in[2];   // entity_mole_weight [NE,NM]
  const float* W1  = (const float*)d_in[3];
  const float* r1  = (const float*)d_in[4];
  const float* b1  = (const float*)d_in[5];
  const float* W2  = (const float*)d_in[6];
  const float* r2  = (const float*)d_in[7];
  const float* b2  = (const float*)d_in[8];
  float* out = (float*)d_out;
  char* ws = (char*)d_ws;

  constexpr size_t OFF_INV  = 0;
  constexpr size_t OFF_XEBF = OFF_INV  + (size_t)NEPAD*8*4;
  constexpr size_t OFF_M1   = OFF_XEBF + (size_t)NEPAD*128*2;
  constexpr size_t OFF_Z1   = OFF_M1   + (size_t)NM*128*2;
  constexpr size_t OFF_Z2   = OFF_Z1   + (size_t)5*128*NM*2;
  constexpr size_t OFF_R1T  = OFF_Z2   + (size_t)5*128*NM*2;
  constexpr size_t OFF_R2T  = OFF_R1T  + 128*128*2;
  constexpr size_t OFF_W1T  = OFF_R2T  + 128*128*2;
  constexpr size_t OFF_W2T  = OFF_W1T  + (size_t)5*128*128*2;
  constexpr size_t OFF_E1   = OFF_W2T  + (size_t)5*128*128*2;
  constexpr size_t OFF_LEV  = OFF_E1   + (size_t)NEPAD*128*2;
  constexpr size_t NEED_LEV = OFF_LEV  + (size_t)NEPAD*NM;   // ~32.4 MB total

  float*    inv  = (float*)   (ws + OFF_INV);
  uint16_t* xebf = (uint16_t*)(ws + OFF_XEBF);
  uint16_t* m1   = (uint16_t*)(ws + OFF_M1);
  uint16_t* z1t  = (uint16_t*)(ws + OFF_Z1);
  uint16_t* z2t  = (uint16_t*)(ws + OFF_Z2);
  uint16_t* r1t  = (uint16_t*)(ws + OFF_R1T);
  uint16_t* r2t  = (uint16_t*)(ws + OFF_R2T);
  uint16_t* w1t  = (uint16_t*)(ws + OFF_W1T);
  uint16_t* w2t  = (uint16_t*)(ws + OFF_W2T);
  uint16_t* e1bf = (uint16_t*)(ws + OFF_E1);
  uint8_t*  lev  = (uint8_t*) (ws + OFF_LEV);

  // If ws can't hold the lev cache, recompute lev from w inside k_conv.
  bool use_lev = (ws_size >= NEED_LEV);

  hipLaunchKernelGGL(k_prep, dim3(768), dim3(256), 0, stream,
                     r1, r2, W1, W2, r1t, r2t, w1t, w2t);
  hipLaunchKernelGGL(k_lev, dim3(NEPAD), dim3(256), 0, stream,
                     w, xe, b1, lev, inv, xebf, out, use_lev ? 1 : 0);
  // m1 = relu(xm @ root1 + b1)
  hipLaunchKernelGGL((k_gemm<false,true,false>), dim3(16,1), dim3(256), 0, stream,
                     xm, (const uint16_t*)nullptr, r1t, b1, m1);
  // Z1t[r] = (xm @ W1[r])^T
  hipLaunchKernelGGL((k_gemm<false,false,true>), dim3(16,5), dim3(256), 0, stream,
                     xm, (const uint16_t*)nullptr, w1t, (const float*)nullptr, z1t);
  // Z2t[r] = (m1 @ W2[r])^T
  hipLaunchKernelGGL((k_gemm<true,false,true>), dim3(16,5), dim3(256), 0, stream,
                     (const float*)nullptr, m1, w2t, (const float*)nullptr, z2t);
  // conv1 -> d_out (pre-initialized with b1)
  if (use_lev)
    hipLaunchKernelGGL((k_conv<true>),  dim3(MTILES, KSPLIT), dim3(256), 0, stream,
                       lev, w, inv, z1t, xebf, r1t, out);
  else
    hipLaunchKernelGGL((k_conv<false>), dim3(MTILES, KSPLIT), dim3(256), 0, stream,
                       lev, w, inv, z1t, xebf, r1t, out);
  // e1 = relu(d_out) -> bf16 ; d_out := b2
  hipLaunchKernelGGL(k_fin, dim3(5056), dim3(256), 0, stream, out, b2, e1bf);
  // conv2 -> d_out
  if (use_lev)
    hipLaunchKernelGGL((k_conv<true>),  dim3(MTILES, KSPLIT), dim3(256), 0, stream,
                       lev, w, inv, z2t, e1bf, r2t, out);
  else
    hipLaunchKernelGGL((k_conv<false>), dim3(MTILES, KSPLIT), dim3(256), 0, stream,
                       lev, w, inv, z2t, e1bf, r2t, out);
}

// Round 2
// 190.309 us; speedup vs baseline: 1.2490x; 1.2490x over previous
//
#include <hip/hip_runtime.h>
#include <stdint.h>

// hetero_effect_graph: 2-layer RGCN over dense level-partitioned bipartite graph.
//  k_prep : transpose+bf16 root1,root2,W1[1..5],W2[1..5]
//  k_lev  : sel = ceil(w*6) in 0..6 packed k-major (levp[k/8][row][8B], coalesced via
//           LDS tile transpose), per-row relation counts -> inv, xe->bf16, out := b1
//  k_gemm : m1 = relu(xm@root1+b1); zpk[r] = (A@W[r]) packed k-major [r][k/8][d][8]
//  k_conv : out += sum_r (inv_r*mask_r) @ Z_r via MFMA; A fragments built with
//           v_perm_b32 byte-table lookups (2 ops/reg); + root slice ks; atomics.
//  k_fin  : e1 = relu(out) -> bf16 (reuses xebf buf), out := b2

#define NE 10000
#define NM 2048
#define NEPAD 10112   // 79 * 128
#define MTILES 79
#define KSPLIT 8

typedef short bf8_t __attribute__((ext_vector_type(8)));
typedef float f16f  __attribute__((ext_vector_type(16)));

__device__ __forceinline__ uint16_t f2bf(float f){
  uint32_t u = __float_as_uint(f);
  u += 0x7FFFu + ((u >> 16) & 1u);
  return (uint16_t)(u >> 16);
}

__device__ __forceinline__ f16f mfma32(bf8_t a, bf8_t b, f16f c){
  return __builtin_amdgcn_mfma_f32_32x32x16_bf16(a, b, c, 0, 0, 0);
}

// ---- transpose + bf16 convert the small weight matrices ----
__global__ __launch_bounds__(256) void k_prep(
    const float* __restrict__ root1, const float* __restrict__ root2,
    const float* __restrict__ W1, const float* __restrict__ W2,
    uint16_t* __restrict__ r1t, uint16_t* __restrict__ r2t,
    uint16_t* __restrict__ w1t, uint16_t* __restrict__ w2t){
  int idx = blockIdx.x*256 + threadIdx.x;
  int slab = idx >> 14;
  int pos  = idx & 16383;
  int d = pos >> 7, k = pos & 127;
  float v; uint16_t* dst;
  if (slab == 0)      { v = root1[k*128 + d]; dst = r1t; }
  else if (slab == 1) { v = root2[k*128 + d]; dst = r2t; }
  else if (slab < 7)  { v = W1[(slab-1)*16384 + k*128 + d]; dst = w1t + (slab-2)*16384; }
  else                { v = W2[(slab-6)*16384 + k*128 + d]; dst = w2t + (slab-7)*16384; }
  dst[pos] = f2bf(v);
}

// ---- 32 rows/block: levp (k-major, coalesced), inv, xe->bf16, out := b1 ----
__global__ __launch_bounds__(256) void k_lev(
    const float* __restrict__ w, const float* __restrict__ xe,
    const float* __restrict__ b1, uint2* __restrict__ levp,
    float* __restrict__ inv, uint16_t* __restrict__ xebf,
    float* __restrict__ out){
  int t = threadIdx.x;
  int brow = blockIdx.x * 32;
  int rloc = t >> 3, p = t & 7;          // 8 threads per row
  int row = brow + rloc;
  bool active = row < NE;
  const float* wr = w + (size_t)row * NM;
  unsigned long long cnt = 0ull;         // 5 x 12-bit packed relation counters
  __shared__ uint2 tile[32][33];

  for (int cp = 0; cp < 8; cp++){        // 8 column-panels of 256 cols
    uint2 packs[4];
    #pragma unroll
    for (int q = 0; q < 4; q++){
      int ckin = p + 8*q;                // chunk within panel
      int gck  = cp*32 + ckin;           // global 8-col chunk
      uint32_t lo = 0, hi = 0;
      if (active){
        const float4* f = (const float4*)(wr + gck*8);
        float4 f0 = f[0], f1 = f[1];
        float wv[8] = {f0.x,f0.y,f0.z,f0.w, f1.x,f1.y,f1.z,f1.w};
        #pragma unroll
        for (int e = 0; e < 8; e++){
          int s = (int)ceilf(wv[e]*6.0f);          // lev+1 in 0..6
          if (s >= 2) cnt += 1ull << (12*(s-2));   // relations 1..5
          uint32_t b = (uint32_t)s;
          if (e < 4) lo |= b << (8*e); else hi |= b << (8*(e-4));
        }
      }
      packs[q] = make_uint2(lo, hi);
    }
    __syncthreads();
    #pragma unroll
    for (int q = 0; q < 4; q++) tile[p + 8*q][rloc] = packs[q];
    __syncthreads();
    // coalesced writeout: thread t -> chunk t>>3, 4 consecutive rows
    int ckk = t >> 3;
    int r4  = (t & 7) * 4;
    size_t base = (size_t)(cp*32 + ckk) * NEPAD + brow + r4;
    levp[base]   = tile[ckk][r4];
    levp[base+1] = tile[ckk][r4+1];
    levp[base+2] = tile[ckk][r4+2];
    levp[base+3] = tile[ckk][r4+3];
  }

  // reduce packed counters across the 8 threads of each row
  unsigned long long c = cnt;
  c += __shfl_xor(c, 1);
  c += __shfl_xor(c, 2);
  c += __shfl_xor(c, 4);
  if (p == 0 && row < NEPAD){
    if (active){
      inv[row*8 + 0] = 0.f; inv[row*8 + 6] = 0.f; inv[row*8 + 7] = 0.f;
      #pragma unroll
      for (int r = 1; r <= 5; r++){
        uint32_t cc = (uint32_t)((c >> (12*(r-1))) & 0xFFFull);
        inv[row*8 + r] = cc ? 1.0f/(float)cc : 0.f;
      }
    } else {
      #pragma unroll
      for (int i = 0; i < 8; i++) inv[row*8 + i] = 0.f;
    }
  }

  // xe -> bf16 (+ zero pads), out := b1
  int f0i = p * 16;
  if (active){
    union { uint16_t u[16]; uint4 q[2]; } ub;
    #pragma unroll
    for (int j = 0; j < 4; j++){
      float4 a = *(const float4*)(xe + (size_t)row*128 + f0i + j*4);
      ub.u[j*4+0]=f2bf(a.x); ub.u[j*4+1]=f2bf(a.y); ub.u[j*4+2]=f2bf(a.z); ub.u[j*4+3]=f2bf(a.w);
      *(float4*)(out + (size_t)row*128 + f0i + j*4) = *(const float4*)(b1 + f0i + j*4);
    }
    *(uint4*)(xebf + (size_t)row*128 + f0i)     = ub.q[0];
    *(uint4*)(xebf + (size_t)row*128 + f0i + 8) = ub.q[1];
  } else if (row < NEPAD){
    uint4 z = make_uint4(0,0,0,0);
    *(uint4*)(xebf + (size_t)row*128 + f0i)     = z;
    *(uint4*)(xebf + (size_t)row*128 + f0i + 8) = z;
  }
}

// ---- small GEMM [2048x128]@[128x128]; epilogue: m1 (bias+relu) or zpk pack ----
template<bool ABF16>
__global__ __launch_bounds__(256) void k_gemm(
    const float* __restrict__ Af, const uint16_t* __restrict__ Ab,
    const uint16_t* __restrict__ Bm, const uint16_t* __restrict__ Bz,
    const float* __restrict__ bias, uint16_t* __restrict__ m1out,
    uint16_t* __restrict__ zpk){
  int tid = threadIdx.x;
  int lane = tid & 63, wid = tid >> 6;
  int l31 = lane & 31, g = lane >> 5;
  int by = blockIdx.y;
  bool m1path = (Bm != nullptr) && (by == 0);
  int r = (Bm != nullptr) ? by - 1 : by;
  const uint16_t* B = m1path ? Bm : (Bz + (size_t)r*16384);
  int arow = blockIdx.x*128 + wid*32 + l31;

  f16f acc[4];
  #pragma unroll
  for (int n = 0; n < 4; n++)
    #pragma unroll
    for (int i = 0; i < 16; i++) acc[n][i] = 0.f;

  #pragma unroll
  for (int ksI = 0; ksI < 8; ksI++){
    int k0 = ksI*16 + g*8;
    bf8_t a;
    if (ABF16){
      a = *(const bf8_t*)(Ab + (size_t)arow*128 + k0);
    } else {
      const float* ap = Af + (size_t)arow*128 + k0;
      float4 f0 = *(const float4*)ap;
      float4 f1 = *(const float4*)(ap + 4);
      union { uint16_t u[8]; bf8_t v; } ua;
      ua.u[0]=f2bf(f0.x); ua.u[1]=f2bf(f0.y); ua.u[2]=f2bf(f0.z); ua.u[3]=f2bf(f0.w);
      ua.u[4]=f2bf(f1.x); ua.u[5]=f2bf(f1.y); ua.u[6]=f2bf(f1.z); ua.u[7]=f2bf(f1.w);
      a = ua.v;
    }
    #pragma unroll
    for (int n = 0; n < 4; n++){
      bf8_t b = *(const bf8_t*)(B + (size_t)(n*32 + l31)*128 + k0);
      acc[n] = mfma32(a, b, acc[n]);
    }
  }
  #pragma unroll
  for (int n = 0; n < 4; n++){
    int colg = n*32 + l31;
    float bv = m1path ? bias[colg] : 0.f;
    #pragma unroll
    for (int v = 0; v < 16; v++){
      int rowl = (v&3) + 8*(v>>2) + 4*g;
      int rg = blockIdx.x*128 + wid*32 + rowl;   // mole index j
      float val = acc[n][v];
      if (m1path){
        m1out[(size_t)rg*128 + colg] = f2bf(fmaxf(val + bv, 0.f));
      } else {
        zpk[(size_t)(r*256 + (rg>>3))*1024 + colg*8 + (rg&7)] = f2bf(val);
      }
    }
  }
}

// ---- masked RGCN conv with perm-built A fragments ----
__global__ __launch_bounds__(256, 2) void k_conv(
    const uint2* __restrict__ levp, const float* __restrict__ inv,
    const uint16_t* __restrict__ zpk, const uint16_t* __restrict__ aroot,
    const uint16_t* __restrict__ rt, float* __restrict__ tgt){
  int tid = threadIdx.x;
  int lane = tid & 63, wid = tid >> 6;
  int wm = wid >> 1, wn = wid & 1;
  int l31 = lane & 31, g = lane >> 5;
  int brow = blockIdx.x*128;
  int ks = blockIdx.y;

  int rg0 = brow + 64*wm + l31;
  int rg1 = rg0 + 32;

  // per-relation byte tables: byte (r+1) of the 8-byte pool = inv_r's lo/hi byte
  uint32_t tlo[2][5], thi[2][5];
  #pragma unroll
  for (int mt = 0; mt < 2; mt++){
    int rg = mt ? rg1 : rg0;
    #pragma unroll
    for (int r = 1; r <= 5; r++){
      uint32_t bits = (uint32_t)f2bf(inv[(size_t)rg*8 + r]);
      int sh = 8*((r+1)&3);
      tlo[mt][r-1] = (bits & 0xFFu) << sh;
      thi[mt][r-1] = (bits >> 8)    << sh;
    }
  }

  f16f acc[2][2];
  #pragma unroll
  for (int a0=0;a0<2;a0++)
    #pragma unroll
    for (int b0=0;b0<2;b0++)
      #pragma unroll
      for (int i=0;i<16;i++) acc[a0][b0][i]=0.f;

  int kb = ks*32 + g;   // base k-tile (8 halfwords each)
  const uint16_t* zr0 = zpk + (size_t)(64*wn      + l31)*8;
  const uint16_t* zr1 = zpk + (size_t)(64*wn + 32 + l31)*8;

  #pragma unroll 2
  for (int kk = 0; kk < 16; kk++){
    int kt = kb + kk*2;
    uint2 L0 = levp[(size_t)kt*NEPAD + rg0];
    uint2 L1 = levp[(size_t)kt*NEPAD + rg1];
    #pragma unroll
    for (int r = 1; r <= 5; r++){
      size_t zb = (size_t)((r-1)*256 + kt) * 1024;
      bf8_t bn0 = *(const bf8_t*)(zr0 + zb);
      bf8_t bn1 = *(const bf8_t*)(zr1 + zb);
      #pragma unroll
      for (int mt = 0; mt < 2; mt++){
        uint32_t sx = mt ? L1.x : L0.x;
        uint32_t sy = mt ? L1.y : L0.y;
        uint32_t TL = tlo[mt][r-1], TH = thi[mt][r-1];
        uint32_t pl0, ph0, pl1, ph1;
        if (r < 3){   // table byte index 2..3 -> low pool (src1)
          pl0 = __builtin_amdgcn_perm(0u, TL, sx);
          ph0 = __builtin_amdgcn_perm(0u, TH, sx);
          pl1 = __builtin_amdgcn_perm(0u, TL, sy);
          ph1 = __builtin_amdgcn_perm(0u, TH, sy);
        } else {      // table byte index 4..6 -> high pool (src0)
          pl0 = __builtin_amdgcn_perm(TL, 0u, sx);
          ph0 = __builtin_amdgcn_perm(TH, 0u, sx);
          pl1 = __builtin_amdgcn_perm(TL, 0u, sy);
          ph1 = __builtin_amdgcn_perm(TH, 0u, sy);
        }
        union { uint32_t u[4]; bf8_t v; } A;
        A.u[0] = __builtin_amdgcn_perm(ph0, pl0, 0x05010400u);
        A.u[1] = __builtin_amdgcn_perm(ph0, pl0, 0x07030602u);
        A.u[2] = __builtin_amdgcn_perm(ph1, pl1, 0x05010400u);
        A.u[3] = __builtin_amdgcn_perm(ph1, pl1, 0x07030602u);
        acc[mt][0] = mfma32(A.v, bn0, acc[mt][0]);
        acc[mt][1] = mfma32(A.v, bn1, acc[mt][1]);
      }
    }
  }

  if (ks < 8){   // this block's root-matmul k-slice (balanced across ks)
    int k0 = ks*16 + g*8;
    bf8_t a0  = *(const bf8_t*)(aroot + (size_t)rg0*128 + k0);
    bf8_t a1  = *(const bf8_t*)(aroot + (size_t)rg1*128 + k0);
    bf8_t rb0 = *(const bf8_t*)(rt + (size_t)(64*wn      + l31)*128 + k0);
    bf8_t rb1 = *(const bf8_t*)(rt + (size_t)(64*wn + 32 + l31)*128 + k0);
    acc[0][0] = mfma32(a0, rb0, acc[0][0]);
    acc[0][1] = mfma32(a0, rb1, acc[0][1]);
    acc[1][0] = mfma32(a1, rb0, acc[1][0]);
    acc[1][1] = mfma32(a1, rb1, acc[1][1]);
  }

  #pragma unroll
  for (int mt = 0; mt < 2; mt++){
    #pragma unroll
    for (int nt = 0; nt < 2; nt++){
      int colg = 64*wn + 32*nt + l31;
      #pragma unroll
      for (int v = 0; v < 16; v++){
        int rowl = (v&3) + 8*(v>>2) + 4*g;
        int rg = brow + 64*wm + 32*mt + rowl;
        if (rg < NE) unsafeAtomicAdd(&tgt[(size_t)rg*128 + colg], acc[mt][nt][v]);
      }
    }
  }
}

// ---- e1 = relu(out) -> bf16 (into xebf buffer); out := b2 ----
__global__ __launch_bounds__(256) void k_fin(
    float* __restrict__ dout, const float* __restrict__ b2,
    uint16_t* __restrict__ e1bf){
  int idx4 = (blockIdx.x*256 + threadIdx.x) * 4;
  float4 v = *(const float4*)(dout + idx4);
  union { uint16_t u[4]; uint2 q; } ub;
  ub.u[0] = f2bf(fmaxf(v.x, 0.f));
  ub.u[1] = f2bf(fmaxf(v.y, 0.f));
  ub.u[2] = f2bf(fmaxf(v.z, 0.f));
  ub.u[3] = f2bf(fmaxf(v.w, 0.f));
  *(uint2*)(e1bf + idx4) = ub.q;
  *(float4*)(dout + idx4) = *(const float4*)(b2 + (idx4 & 127));
}

extern "C" void kernel_launch(void* const* d_in, const int* in_sizes, int n_in,
                              void* d_out, int out_size, void* d_ws, size_t ws_size,
                              hipStream_t stream){
  const float* xe  = (const float*)d_in[0];
  const float* xm  = (const float*)d_in[1];
  const float* w   = (const float*)d_in[2];
  const float* W1  = (const float*)d_in[3];
  const float* r1  = (const float*)d_in[4];
  const float* b1  = (const float*)d_in[5];
  const float* W2  = (const float*)d_in[6];
  const float* r2  = (const float*)d_in[7];
  const float* b2  = (const float*)d_in[8];
  float* out = (float*)d_out;
  char* ws = (char*)d_ws;

  constexpr size_t OFF_INV  = 0;                                   // NEPAD*8*4
  constexpr size_t OFF_XEBF = OFF_INV  + (size_t)NEPAD*8*4;        // NEPAD*128*2 (also e1bf)
  constexpr size_t OFF_M1   = OFF_XEBF + (size_t)NEPAD*128*2;      // NM*128*2
  constexpr size_t OFF_ZPK  = OFF_M1   + (size_t)NM*128*2;         // 5*NM*128*2 (z1 then z2)
  constexpr size_t OFF_R1T  = OFF_ZPK  + (size_t)5*NM*128*2;
  constexpr size_t OFF_R2T  = OFF_R1T  + 128*128*2;
  constexpr size_t OFF_W1T  = OFF_R2T  + 128*128*2;
  constexpr size_t OFF_W2T  = OFF_W1T  + (size_t)5*128*128*2;
  constexpr size_t OFF_LEVP = OFF_W2T  + (size_t)5*128*128*2;      // 256*NEPAD*8  (~20.7MB)

  float*    inv  = (float*)   (ws + OFF_INV);
  uint16_t* xebf = (uint16_t*)(ws + OFF_XEBF);
  uint16_t* m1   = (uint16_t*)(ws + OFF_M1);
  uint16_t* zpk  = (uint16_t*)(ws + OFF_ZPK);
  uint16_t* r1t  = (uint16_t*)(ws + OFF_R1T);
  uint16_t* r2t  = (uint16_t*)(ws + OFF_R2T);
  uint16_t* w1t  = (uint16_t*)(ws + OFF_W1T);
  uint16_t* w2t  = (uint16_t*)(ws + OFF_W2T);
  uint2*    levp = (uint2*)   (ws + OFF_LEVP);

  hipLaunchKernelGGL(k_prep, dim3(768), dim3(256), 0, stream,
                     r1, r2, W1, W2, r1t, r2t, w1t, w2t);
  hipLaunchKernelGGL(k_lev, dim3(NEPAD/32), dim3(256), 0, stream,
                     w, xe, b1, levp, inv, xebf, out);
  // y=0: m1 = relu(xm@root1+b1); y=1..5: zpk[y-1] = pack(xm@W1[y-1])
  hipLaunchKernelGGL((k_gemm<false>), dim3(16,6), dim3(256), 0, stream,
                     xm, (const uint16_t*)nullptr, r1t, w1t, b1, m1, zpk);
  // conv1 -> out (pre-initialized with b1)
  hipLaunchKernelGGL(k_conv, dim3(MTILES, KSPLIT), dim3(256), 0, stream,
                     levp, inv, zpk, xebf, r1t, out);
  // e1 = relu(out) -> xebf buffer ; out := b2
  hipLaunchKernelGGL(k_fin, dim3(NE*128/1024), dim3(256), 0, stream, out, b2, xebf);
  // zpk[r] = pack(m1@W2[r])  (overwrites z1 after conv1 done)
  hipLaunchKernelGGL((k_gemm<true>), dim3(16,5), dim3(256), 0, stream,
                     (const float*)nullptr, m1, (const uint16_t*)nullptr, w2t,
                     (const float*)nullptr, (uint16_t*)nullptr, zpk);
  // conv2 -> out
  hipLaunchKernelGGL(k_conv, dim3(MTILES, KSPLIT), dim3(256), 0, stream,
                     levp, inv, zpk, xebf, r2t, out);
}